// Round 10
// baseline (63.762 us; speedup 1.0000x reference)
//
#include <hip/hip_runtime.h>

// CRF-RNN collapsed: out[t,i] = sum_j M[i,j] * orig[t,j],
//   orig[t,j] = sum_m inputs[t,j,m]*W_feat[m]
//   M = (I + B + B^2 + B^3) * diag(1/denom) + B^4
// Pipeline:
//   k_prep -> B, Einv          k_mm -> C=B^2        k_mm2 -> G1=B*C, G2=C*C
//   k_comb -> Mh/Ml (split bf16)
//   k_orig -> feature-reduce input, split bf16, write SWIZZLED A-tiles into
//             d_out (scratch; block-local, fully overwritten each call)
//   k_gemm -> stage A-tile + M-panels via global_load_lds, MFMA, write out

#define NREG 256   // N
#define KG   16    // gaussian kernels
#define MF   8     // features

typedef unsigned short u16;
typedef __attribute__((ext_vector_type(8))) short short8;   // 8 bf16 = 4 VGPR
typedef __attribute__((ext_vector_type(4))) float f32x4;

__device__ __forceinline__ void async_copy16(const void* g, void* l) {
    __builtin_amdgcn_global_load_lds(
        (const __attribute__((address_space(1))) void*)g,
        (__attribute__((address_space(3))) void*)l,
        16, 0, 0);
}

__device__ __forceinline__ u16 bf16_rne(float x) {
    unsigned u = __float_as_uint(x);
    return (u16)((u + 0x7FFFu + ((u >> 16) & 1u)) >> 16);
}
__device__ __forceinline__ float bf16_to_f(u16 h) {
    return __uint_as_float(((unsigned)h) << 16);
}

// ---------------- K1: Kmat row, denom, B, Einv ----------------
__global__ __launch_bounds__(256) void k_prep(const float* __restrict__ kern,
                                              const float* __restrict__ Wlin,
                                              const float* __restrict__ Wfeat,
                                              float* __restrict__ B,
                                              float* __restrict__ Einv) {
    const int i = blockIdx.x, j = threadIdx.x;
    const float* kp = kern + ((size_t)i * NREG + j) * KG;
    float4 w0 = *(const float4*)(Wlin + 0);
    float4 w1 = *(const float4*)(Wlin + 4);
    float4 w2 = *(const float4*)(Wlin + 8);
    float4 w3 = *(const float4*)(Wlin + 12);
    float4 v0 = *(const float4*)(kp + 0);
    float4 v1 = *(const float4*)(kp + 4);
    float4 v2 = *(const float4*)(kp + 8);
    float4 v3 = *(const float4*)(kp + 12);
    float km = v0.x*w0.x + v0.y*w0.y + v0.z*w0.z + v0.w*w0.w
             + v1.x*w1.x + v1.y*w1.y + v1.z*w1.z + v1.w*w1.w
             + v2.x*w2.x + v2.y*w2.y + v2.z*w2.z + v2.w*w2.w
             + v3.x*w3.x + v3.y*w3.y + v3.z*w3.z + v3.w*w3.w;

    __shared__ float red[256];
    red[j] = km;
    __syncthreads();
    for (int s = 128; s > 0; s >>= 1) {
        if (j < s) red[j] += red[j + s];
        __syncthreads();
    }
    __shared__ float sden;
    if (j == 0) {
        float fw = 0.f;
#pragma unroll
        for (int m = 0; m < MF; ++m) fw += Wfeat[m];
        float den = fw + 2.f * red[0];
        sden = den;
        Einv[i] = 1.f / den;
    }
    __syncthreads();
    B[(size_t)i * NREG + j] = 2.f * km / sden;
}

// ---------------- 2-row matmul body (Out rows i0,i0+1 = A rows * Bm) -------
__device__ __forceinline__ void mm2rows(const float* __restrict__ A,
                                        const float* __restrict__ Bm,
                                        float* __restrict__ Out,
                                        int i0, int tid) {
    __shared__ float Ar[2][NREG];
    Ar[0][tid] = A[(size_t)i0 * NREG + tid];
    Ar[1][tid] = A[(size_t)(i0 + 1) * NREG + tid];
    __syncthreads();
    float acc0 = 0.f, acc1 = 0.f;
#pragma unroll 2
    for (int l = 0; l < NREG; l += 8) {
        float b0 = Bm[(size_t)(l + 0) * NREG + tid];
        float b1 = Bm[(size_t)(l + 1) * NREG + tid];
        float b2 = Bm[(size_t)(l + 2) * NREG + tid];
        float b3 = Bm[(size_t)(l + 3) * NREG + tid];
        float b4 = Bm[(size_t)(l + 4) * NREG + tid];
        float b5 = Bm[(size_t)(l + 5) * NREG + tid];
        float b6 = Bm[(size_t)(l + 6) * NREG + tid];
        float b7 = Bm[(size_t)(l + 7) * NREG + tid];
        acc0 += Ar[0][l+0]*b0 + Ar[0][l+1]*b1 + Ar[0][l+2]*b2 + Ar[0][l+3]*b3
              + Ar[0][l+4]*b4 + Ar[0][l+5]*b5 + Ar[0][l+6]*b6 + Ar[0][l+7]*b7;
        acc1 += Ar[1][l+0]*b0 + Ar[1][l+1]*b1 + Ar[1][l+2]*b2 + Ar[1][l+3]*b3
              + Ar[1][l+4]*b4 + Ar[1][l+5]*b5 + Ar[1][l+6]*b6 + Ar[1][l+7]*b7;
    }
    Out[(size_t)i0 * NREG + tid] = acc0;
    Out[(size_t)(i0 + 1) * NREG + tid] = acc1;
}

// K2: C = B*B   (grid 128, 2 rows/block)
__global__ __launch_bounds__(256) void k_mm(const float* __restrict__ A,
                                            const float* __restrict__ Bm,
                                            float* __restrict__ Out) {
    mm2rows(A, Bm, Out, blockIdx.x * 2, threadIdx.x);
}

// K3: G1 = B*C (blocks 0..127), G2 = C*C (blocks 128..255)
__global__ __launch_bounds__(256) void k_mm2(const float* __restrict__ B,
                                             const float* __restrict__ C,
                                             float* __restrict__ G1,
                                             float* __restrict__ G2) {
    const bool second = blockIdx.x >= 128;
    mm2rows(second ? C : B, C, second ? G2 : G1, (blockIdx.x & 127) * 2,
            threadIdx.x);
}

// K4: M[i][j] (fp32) -> split bf16 Mh/Ml, row-major [i][j]
__global__ __launch_bounds__(256) void k_comb(const float* __restrict__ B,
                                              const float* __restrict__ C,
                                              const float* __restrict__ G1,
                                              const float* __restrict__ G2,
                                              const float* __restrict__ Einv,
                                              u16* __restrict__ Mh,
                                              u16* __restrict__ Ml) {
    const int i = blockIdx.x, j = threadIdx.x;
    const size_t idx = (size_t)i * NREG + j;
    float v = ((i == j) ? 1.f : 0.f) + B[idx] + C[idx] + G1[idx];
    v = v * Einv[j] + G2[idx];
    u16 h = bf16_rne(v);
    float lo = v - bf16_to_f(h);
    Mh[idx] = h;
    Ml[idx] = bf16_rne(lo);
}

// ---------------- K5: feature-reduce -> swizzled split-bf16 A-tiles --------
// Pure elementwise stream: grid 2048 x 256 thr, 16 independent loads issued
// up-front per thread, no LDS, no async. Writes into d_out as scratch:
//   tile g (64 t-rows) at bytes [g*64K, g*64K+64K): Ah-tile 32K then Al-tile
//   32K; u16 index within tile = tl*256 + (chunk^(tl&7))*8 + (j&7).
// Each lane handles 2 adjacent cells -> one u32 write per array (coalesced,
// chunk-XOR permutes 16B-chunks only within 128B windows).
__global__ __launch_bounds__(256, 4) void k_orig(const float* __restrict__ in,
                                                 const float* __restrict__ Wfeat,
                                                 u16* __restrict__ Aout) {
    const int tid = threadIdx.x, lane = tid & 63, wid = tid >> 6;
    float4 wa = *(const float4*)(Wfeat);
    float4 wb = *(const float4*)(Wfeat + 4);

    const int hr0 = blockIdx.x * 16 + wid * 4;   // 4 half-rows per wave
    float4 v[4][4];
#pragma unroll
    for (int it = 0; it < 4; ++it) {
        const int hr = hr0 + it;
        const size_t base = (size_t)(hr >> 1) * 2048 + (size_t)(hr & 1) * 1024
                          + lane * 16;
#pragma unroll
        for (int q = 0; q < 4; ++q)
            v[it][q] = *(const float4*)(in + base + q * 4);
    }
#pragma unroll
    for (int it = 0; it < 4; ++it) {
        const int hr = hr0 + it;
        const int t = hr >> 1, half = hr & 1;
        const int tl = t & 63, g = t >> 6;
        float o0 = v[it][0].x*wa.x + v[it][0].y*wa.y + v[it][0].z*wa.z + v[it][0].w*wa.w
                 + v[it][1].x*wb.x + v[it][1].y*wb.y + v[it][1].z*wb.z + v[it][1].w*wb.w;
        float o1 = v[it][2].x*wa.x + v[it][2].y*wa.y + v[it][2].z*wa.z + v[it][2].w*wa.w
                 + v[it][3].x*wb.x + v[it][3].y*wb.y + v[it][3].z*wb.z + v[it][3].w*wb.w;
        u16 h0 = bf16_rne(o0), l0 = bf16_rne(o0 - bf16_to_f(h0));
        u16 h1 = bf16_rne(o1), l1 = bf16_rne(o1 - bf16_to_f(h1));
        const int j0 = half * 128 + 2 * lane;
        const int swz = (j0 >> 3) ^ (tl & 7);
        const int idx = tl * 256 + swz * 8 + (j0 & 7);      // even -> 4B aligned
        char* tile = (char*)Aout + (size_t)g * 65536;
        *(unsigned*)(tile + idx * 2)         = ((unsigned)h1 << 16) | h0;
        *(unsigned*)(tile + 32768 + idx * 2) = ((unsigned)l1 << 16) | l0;
    }
}

// ---------------- K6: MFMA GEMM (r9-verified stage-2) ----------------------
// 512 thr (8 waves), 64 t-rows/block, grid 256. LDS 128 KB:
//   Ah/Al [64][256] staged linearly via 64 gll from this block's d_out tile;
//   Bh/Bl [256][64] single-buffered panel, 4 panels of 64 j.
__global__ __launch_bounds__(512, 1) void k_gemm(const u16* __restrict__ Mh,
                                                 const u16* __restrict__ Ml,
                                                 float* out) {
    __shared__ __align__(16) u16 Ah[64 * 256];   // 32 KB
    __shared__ __align__(16) u16 Al[64 * 256];   // 32 KB
    __shared__ __align__(16) u16 Bh[256 * 64];   // 32 KB
    __shared__ __align__(16) u16 Bl[256 * 64];   // 32 KB
    const int tid = threadIdx.x, lane = tid & 63, wid = tid >> 6;  // wid 0..7
    const int g = blockIdx.x;
    const size_t t0 = (size_t)g * 64;
    const char* tile = (const char*)out + (size_t)g * 65536;  // this block's A

    // stage A: 64 x 1KB linear copies (8 per wave)
#pragma unroll
    for (int s = 0; s < 4; ++s) {
        const int k = s * 8 + wid;               // 0..31
        async_copy16(tile + k * 1024 + lane * 16,         (char*)Ah + k * 1024);
        async_copy16(tile + 32768 + k * 1024 + lane * 16, (char*)Al + k * 1024);
    }
    // stage B panel 0 (r9-verified mapping)
#pragma unroll
    for (int s = 0; s < 8; ++s) {
        const int gg = s * 8 + wid;              // 0..63
        const int i0 = (gg & 31) * 8;
        const u16* sg = (gg >> 5) ? Ml : Mh;
        u16* dg = (gg >> 5) ? Bl : Bh;
        const int irow = i0 + (lane >> 3);
        const int ch = (lane & 7) ^ (lane >> 3);
        async_copy16(sg + (size_t)irow * NREG + 0 * 64 + ch * 8, dg + i0 * 64);
    }
    __syncthreads();     // drains vmcnt -> A + panel0 resident

    const int mrow = (wid >> 1) * 16 + (lane & 15);
    const int nh   = (wid & 1) * 8;
    f32x4 acc[8];
#pragma unroll
    for (int n = 0; n < 8; ++n) acc[n] = (f32x4){0.f, 0.f, 0.f, 0.f};

    for (int p = 0; p < 4; ++p) {
#pragma unroll
        for (int kst = 0; kst < 2; ++kst) {
            const int achunk = (8 * p + 4 * kst + (lane >> 4)) ^ (lane & 7);
            short8 a_h = *(const short8*)(Ah + mrow * 256 + achunk * 8);
            short8 a_l = *(const short8*)(Al + mrow * 256 + achunk * 8);
#pragma unroll
            for (int n = 0; n < 8; ++n) {
                const int irow = (nh + n) * 16 + (lane & 15);
                const int bchunk = (4 * kst + (lane >> 4)) ^ (lane & 7);
                short8 b_h = *(const short8*)(Bh + irow * 64 + bchunk * 8);
                short8 b_l = *(const short8*)(Bl + irow * 64 + bchunk * 8);
                acc[n] = __builtin_amdgcn_mfma_f32_16x16x32_bf16(a_h, b_h, acc[n], 0, 0, 0);
                acc[n] = __builtin_amdgcn_mfma_f32_16x16x32_bf16(a_h, b_l, acc[n], 0, 0, 0);
                acc[n] = __builtin_amdgcn_mfma_f32_16x16x32_bf16(a_l, b_h, acc[n], 0, 0, 0);
            }
        }
        if (p < 3) {
            __syncthreads();     // all waves done reading panel p
#pragma unroll
            for (int s = 0; s < 8; ++s) {
                const int gg = s * 8 + wid;
                const int i0 = (gg & 31) * 8;
                const u16* sg = (gg >> 5) ? Ml : Mh;
                u16* dg = (gg >> 5) ? Bl : Bh;
                const int irow = i0 + (lane >> 3);
                const int ch = (lane & 7) ^ (lane >> 3);
                async_copy16(sg + (size_t)irow * NREG + (p + 1) * 64 + ch * 8,
                             dg + i0 * 64);
            }
            __syncthreads();     // panel p+1 resident
        }
    }

    // epilogue: D col = lane&15 (i), row = (lane>>4)*4 + reg (t)
    const size_t tbase = t0 + (wid >> 1) * 16 + (lane >> 4) * 4;
#pragma unroll
    for (int n = 0; n < 8; ++n) {
#pragma unroll
        for (int r = 0; r < 4; ++r) {
            out[(tbase + r) * NREG + (nh + n) * 16 + (lane & 15)] = acc[n][r];
        }
    }
}

extern "C" void kernel_launch(void* const* d_in, const int* in_sizes, int n_in,
                              void* d_out, int out_size, void* d_ws, size_t ws_size,
                              hipStream_t stream) {
    const float* inputs  = (const float*)d_in[0];  // (16384, 256, 8)
    const float* kernels = (const float*)d_in[1];  // (256, 256, 16)
    const float* Wfeat   = (const float*)d_in[2];  // (1, 8)
    const float* Wlin    = (const float*)d_in[3];  // (1, 16)
    float* out = (float*)d_out;                    // (16384, 256)

    float* ws   = (float*)d_ws;                    // ~1.26 MB
    float* B    = ws;                              // 65536 f
    float* C    = B  + NREG * NREG;                // 65536 f (B^2)
    float* G1   = C  + NREG * NREG;                // 65536 f (B^3)
    float* G2   = G1 + NREG * NREG;                // 65536 f (B^4)
    float* Einv = G2 + NREG * NREG;                // 256 f
    u16*   Mh   = (u16*)(Einv + NREG);             // 65536 u16 (16B-aligned)
    u16*   Ml   = Mh + NREG * NREG;                // 65536 u16

    k_prep<<<256, 256, 0, stream>>>(kernels, Wlin, Wfeat, B, Einv);
    k_mm  <<<128, 256, 0, stream>>>(B, B, C);
    k_mm2 <<<256, 256, 0, stream>>>(B, C, G1, G2);
    k_comb<<<256, 256, 0, stream>>>(B, C, G1, G2, Einv, Mh, Ml);
    k_orig<<<2048, 256, 0, stream>>>(inputs, Wfeat, (u16*)d_out);
    k_gemm<<<256, 512, 0, stream>>>(Mh, Ml, out);
}